// Round 3
// baseline (208.577 us; speedup 1.0000x reference)
//
#include <hip/hip_runtime.h>

// Problem constants
constexpr int BATCH = 64;     // M
constexpr int IC    = 8192;   // K
constexpr int OC    = 8192;   // N
constexpr int OCH   = 4096;   // packed rows (OC/2)
constexpr int KSPLIT = 4;
constexpr int KPER  = IC / KSPLIT;   // 2048
constexpr int BK    = 128;           // K-chunk staged in LDS
constexpr int NITER = KPER / BK;     // 16
constexpr int LDK   = BK + 8;        // 136: keeps the conflict-free bank rotation

typedef __bf16 bf16x8 __attribute__((ext_vector_type(8)));
typedef float  f32x4  __attribute__((ext_vector_type(4)));
typedef int    i32x4  __attribute__((ext_vector_type(4)));

// fp32 -> bf16 round-to-nearest-even
static __device__ __forceinline__ unsigned short f2bf(float f) {
    unsigned u = __float_as_uint(f);
    u += 0x7FFFu + ((u >> 16) & 1u);
    return (unsigned short)(u >> 16);
}

// (bf16(n1)<<16) | bf16(n0) for small ints 0..15 (fp32 truncation exact)
static __device__ __forceinline__ unsigned pack2bf(int n0, int n1) {
    unsigned f0 = __float_as_uint((float)n0);
    unsigned f1 = __float_as_uint((float)n1);
    return __builtin_amdgcn_perm(f1, f0, 0x07060302u);
}

// ---------------------------------------------------------------------------
// Prep: input fp32 [64,8192] -> bf16 in ws, plus per-row partial sums
// S4[64][4]. 256 blocks = quarter-row each.
// ---------------------------------------------------------------------------
__global__ __launch_bounds__(256) void prep_kernel(
    const float* __restrict__ in, unsigned short* __restrict__ Abf,
    float* __restrict__ S4)
{
    const int b   = blockIdx.x;        // 0..255
    const int row = b >> 2;
    const int q   = b & 3;
    const int t   = threadIdx.x;
    const float*          rp = in  + (size_t)row * IC + q * 2048;
    unsigned short*       op = Abf + (size_t)row * IC + q * 2048;

    float sum = 0.f;
#pragma unroll
    for (int i = 0; i < 2; ++i) {
        const int c = i * 1024 + t * 4;
        const float4 v = *(const float4*)(rp + c);
        sum += (v.x + v.y) + (v.z + v.w);
        ushort4 o = make_ushort4(f2bf(v.x), f2bf(v.y), f2bf(v.z), f2bf(v.w));
        *(ushort4*)(op + c) = o;
    }
#pragma unroll
    for (int off = 32; off > 0; off >>= 1) sum += __shfl_down(sum, off);

    __shared__ float red[4];
    if ((t & 63) == 0) red[t >> 6] = sum;
    __syncthreads();
    if (t == 0) S4[row * 4 + q] = (red[0] + red[1]) + (red[2] + red[3]);
}

// ---------------------------------------------------------------------------
// Init: out[m][ch] = bias[ch] - delta[ch]*zp[ch]*S[m]  (gemm atomicAdds the
// delta-scaled dot products on top). Fully overwrites d_out.
// ---------------------------------------------------------------------------
__global__ __launch_bounds__(256) void init_kernel(
    const float* __restrict__ delta,
    const float* __restrict__ zp,
    const float* __restrict__ bias,
    const float* __restrict__ S4,     // [64][4]
    float* __restrict__ out)          // [64][8192]
{
    const int e  = (blockIdx.x * 256 + threadIdx.x) * 4;
    const int m  = e >> 13;           // / 8192
    const int ch = e & (OC - 1);

    const float4 d = *(const float4*)(delta + ch);
    const float4 z = *(const float4*)(zp + ch);
    const float4 b = *(const float4*)(bias + ch);
    const float Sm = (S4[m * 4 + 0] + S4[m * 4 + 1]) + (S4[m * 4 + 2] + S4[m * 4 + 3]);

    float4 o;
    o.x = b.x - d.x * z.x * Sm;
    o.y = b.y - d.y * z.y * Sm;
    o.z = b.z - d.z * z.z * Sm;
    o.w = b.w - d.w * z.w * Sm;
    *(float4*)(out + e) = o;
}

// ---------------------------------------------------------------------------
// GEMM: out[m][ch] += delta[ch] * (A.Q^T)[m][ch] over this split's K-range.
// 512 blocks (128 n-tiles x 4 k-splits) x 512 threads (8 waves, 2 blocks/CU).
// Tile M=64 x N=64. Quadrant wave mapping: wave (kh, mq, nq) owns a 32x32
// quadrant of its K-half -> 8 fragment ds_reads/iter (A redundancy 2x, B 2x)
// vs 10 for the column mapping. kh halves cross-reduce via LDS at the end.
// Depth-2 register prefetch + raw s_barrier with lgkmcnt-only wait keeps
// global loads in flight across barriers (no vmcnt(0) drain in the loop).
// Weight loads non-temporal (streamed once; don't evict the A panel from L2).
// ---------------------------------------------------------------------------
__global__ __launch_bounds__(512, 4) void gemm_kernel(
    const unsigned short* __restrict__ Abf,   // bf16 [64][8192]
    const int* __restrict__ wp,               // packed [4096][8192]
    const float* __restrict__ delta,          // [8192]
    float* __restrict__ out)                  // fp32 [64][8192]
{
    __shared__ unsigned short lA[2][64 * LDK];
    __shared__ unsigned short lW[2][64 * LDK];  // rows 0..31 lo nibble, 32..63 hi

    const int t    = threadIdx.x;
    const int lane = t & 63;
    const int lm   = lane & 15;
    const int lq   = lane >> 4;
    const int wv   = t >> 6;         // 0..7
    const int kh   = wv >> 2;        // K-half 0/1
    const int mq   = (wv >> 1) & 1;  // M-quadrant
    const int nq   = wv & 1;         // N-quadrant

    const int nt  = blockIdx.x & 127;
    const int ks  = blockIdx.x >> 7;
    const int r0  = nt * 32;
    const int kb0 = ks * KPER;

    f32x4 acc[2][2];
    const f32x4 zero4 = {0.f, 0.f, 0.f, 0.f};
#pragma unroll
    for (int i = 0; i < 2; ++i)
#pragma unroll
        for (int j = 0; j < 2; ++j) acc[i][j] = zero4;

    // staging maps: A: 64 rows x 8 segs of 16 bf16; W: 32 rows x 16 segs of 8 ints
    const int uAr = t >> 3, uAc = (t & 7) * 16;
    const int uWr = t >> 4, uWc = (t & 15) * 8;

    const unsigned short* pA = Abf + (size_t)uAr * IC + kb0 + uAc;
    const int*            pW = wp  + (size_t)(r0 + uWr) * IC + kb0 + uWc;

    // LDS offsets (ushort units)
    const int sAo   = uAr * LDK + uAc;
    const int sWoLo = uWr * LDK + uWc;
    const int sWoHi = (uWr + 32) * LDK + uWc;
    const int fAo   = (mq * 32 + lm) * LDK + kh * 64 + lq * 8;
    const int fBo   = (nq * 32 + lm) * LDK + kh * 64 + lq * 8;

    i32x4 aA0, aA1, wA0, wA1;   // register set A (even chunks)
    i32x4 aB0, aB1, wB0, wB1;   // register set B (odd chunks)

    // K-loop barrier: lgkmcnt-only; vmcnt deliberately NOT drained.
#define KBAR() { asm volatile("s_waitcnt lgkmcnt(0)" ::: "memory"); \
                 __builtin_amdgcn_s_barrier(); }

#define LOADG(sa0, sa1, sw0, sw1, koff)                                  \
    sa0 = *(const i32x4*)(pA + (koff));                                  \
    sa1 = *(const i32x4*)(pA + (koff) + 8);                              \
    sw0 = __builtin_nontemporal_load((const i32x4*)(pW + (koff)));       \
    sw1 = __builtin_nontemporal_load((const i32x4*)(pW + (koff) + 4));

#define STAGE(buf, sa0, sa1, sw0, sw1) {             \
    *(i32x4*)(&lA[buf][sAo])     = sa0;              \
    *(i32x4*)(&lA[buf][sAo + 8]) = sa1;              \
    i32x4 lo_, hi_;                                  \
    lo_[0] = pack2bf(sw0[0] & 15, sw0[1] & 15);      \
    lo_[1] = pack2bf(sw0[2] & 15, sw0[3] & 15);      \
    lo_[2] = pack2bf(sw1[0] & 15, sw1[1] & 15);      \
    lo_[3] = pack2bf(sw1[2] & 15, sw1[3] & 15);      \
    hi_[0] = pack2bf(sw0[0] >> 4, sw0[1] >> 4);      \
    hi_[1] = pack2bf(sw0[2] >> 4, sw0[3] >> 4);      \
    hi_[2] = pack2bf(sw1[0] >> 4, sw1[1] >> 4);      \
    hi_[3] = pack2bf(sw1[2] >> 4, sw1[3] >> 4);      \
    *(i32x4*)(&lW[buf][sWoLo]) = lo_;                \
    *(i32x4*)(&lW[buf][sWoHi]) = hi_; }

#define MM(p) {                                                                   \
    _Pragma("unroll")                                                             \
    for (int s = 0; s < 2; ++s) {                                                 \
        const bf16x8 b0 = *(const bf16x8*)(&lW[p][fBo + s * 32]);                 \
        const bf16x8 b1 = *(const bf16x8*)(&lW[p][fBo + 16 * LDK + s * 32]);      \
        const bf16x8 a0 = *(const bf16x8*)(&lA[p][fAo + s * 32]);                 \
        const bf16x8 a1 = *(const bf16x8*)(&lA[p][fAo + 16 * LDK + s * 32]);      \
        acc[0][0] = __builtin_amdgcn_mfma_f32_16x16x32_bf16(a0, b0, acc[0][0], 0, 0, 0); \
        acc[0][1] = __builtin_amdgcn_mfma_f32_16x16x32_bf16(a0, b1, acc[0][1], 0, 0, 0); \
        acc[1][0] = __builtin_amdgcn_mfma_f32_16x16x32_bf16(a1, b0, acc[1][0], 0, 0, 0); \
        acc[1][1] = __builtin_amdgcn_mfma_f32_16x16x32_bf16(a1, b1, acc[1][1], 0, 0, 0); \
    } }

    // ---- prologue: chunks 0 and 1 in flight; stage chunk 0 ----
    LOADG(aA0, aA1, wA0, wA1, 0);
    LOADG(aB0, aB1, wB0, wB1, BK);
    STAGE(0, aA0, aA1, wA0, wA1);
    KBAR();

    // ---- main loop: 7 pairs covering it = 0..13; issues chunks 2..15 ----
    for (int it2 = 0; it2 < (NITER - 2) / 2; ++it2) {
        {   // even it: compute buf0, issue chunk it+2 -> setA, stage setB -> buf1
            const int koff = (2 * it2 + 2) * BK;
            LOADG(aA0, aA1, wA0, wA1, koff);
            MM(0);
            STAGE(1, aB0, aB1, wB0, wB1);
            KBAR();
        }
        {   // odd it: compute buf1, issue chunk it+2 -> setB, stage setA -> buf0
            const int koff = (2 * it2 + 3) * BK;
            LOADG(aB0, aB1, wB0, wB1, koff);
            MM(1);
            STAGE(0, aA0, aA1, wA0, wA1);
            KBAR();
        }
    }
    // it = NITER-2: compute buf0, stage chunk 15 (setB) -> buf1 (no issue)
    MM(0);
    STAGE(1, aB0, aB1, wB0, wB1);
    KBAR();
    // it = NITER-1: compute buf1
    MM(1);

#undef LOADG
#undef STAGE
#undef MM
#undef KBAR

    // ---- epilogue: cross-reduce kh halves via LDS, then fused-affine
    //      atomic accumulate into out ----
    __syncthreads();                       // all LDS reads of lA/lW done
    f32x4* lR = (f32x4*)(&lA[0][0]);       // 16 KiB scratch
    const int o = ((wv & 3) * 64 + lane) << 2;
    if (kh) {
        lR[o + 0] = acc[0][0];
        lR[o + 1] = acc[0][1];
        lR[o + 2] = acc[1][0];
        lR[o + 3] = acc[1][1];
    }
    __syncthreads();
    if (!kh) {
        acc[0][0] += lR[o + 0];
        acc[0][1] += lR[o + 1];
        acc[1][0] += lR[o + 2];
        acc[1][1] += lR[o + 3];

        // C/D layout: col(n) = lane&15, row(m within 16-tile) = lq*4 + reg.
        // Wave quadrant: cols nq*32 + nt2*16 + lm; rows mq*32 + mt2*16 + lq*4+r.
#pragma unroll
        for (int nt2 = 0; nt2 < 2; ++nt2) {
            const int ch = (nq ? OCH : 0) + r0 + nt2 * 16 + lm;
            const float d = delta[ch];
            float* po = out + ch;
#pragma unroll
            for (int mt2 = 0; mt2 < 2; ++mt2) {
#pragma unroll
                for (int r = 0; r < 4; ++r) {
                    const int m = mq * 32 + mt2 * 16 + lq * 4 + r;
                    atomicAdd(po + (size_t)m * OC, d * acc[mt2][nt2][r]);
                }
            }
        }
    }
}

extern "C" void kernel_launch(void* const* d_in, const int* in_sizes, int n_in,
                              void* d_out, int out_size, void* d_ws, size_t ws_size,
                              hipStream_t stream) {
    const float* input = (const float*)d_in[0];
    const int*   wpk   = (const int*)d_in[1];
    const float* delta = (const float*)d_in[2];
    const float* zp    = (const float*)d_in[3];
    const float* bias  = (const float*)d_in[4];
    float* out = (float*)d_out;

    // ws layout: Abf (1 MiB) | S4 (1 KiB)
    unsigned short* Abf = (unsigned short*)d_ws;
    float* S4   = (float*)((char*)d_ws + (size_t)BATCH * IC * 2);

    prep_kernel<<<dim3(256), dim3(256), 0, stream>>>(input, Abf, S4);
    init_kernel<<<dim3(BATCH * OC / 1024), dim3(256), 0, stream>>>(delta, zp, bias, S4, out);
    gemm_kernel<<<dim3(128 * KSPLIT), dim3(512), 0, stream>>>(Abf, wpk, delta, out);
}